// Round 6
// baseline (654.136 us; speedup 1.0000x reference)
//
#include <hip/hip_runtime.h>
#include <hip/hip_bf16.h>
#include <math.h>

#define N_NODES 20000
#define N_EDGES 640000
#define ET_EDGES (N_EDGES + N_NODES)   // with self-loops
#define G_GRAPHS 64
#define NEG_SLOPE 0.2f

// ---------------- CSR construction (+ graph bounds folded in) ----------------

__global__ void hist_dst(const int* __restrict__ ei, int* __restrict__ cnt,
                         const int* __restrict__ batch, int* __restrict__ gstart) {
    int j = blockIdx.x * blockDim.x + threadIdx.x;
    if (blockIdx.x == 0 && threadIdx.x <= G_GRAPHS) {
        int g = threadIdx.x;
        int lo = 0, hi = N_NODES;
        while (lo < hi) {              // first i with batch[i] >= g
            int mid = (lo + hi) >> 1;
            if (batch[mid] < g) lo = mid + 1; else hi = mid;
        }
        gstart[g] = lo;
    }
    if (j >= ET_EDGES) return;
    int d = (j < N_EDGES) ? ei[N_EDGES + j] : (j - N_EDGES);
    atomicAdd(&cnt[d], 1);
}

__global__ __launch_bounds__(1024) void scan_rowptr(const int* __restrict__ cnt,
                                                    int* __restrict__ row_ptr) {
    __shared__ int sums[1024];
    const int n = N_NODES;
    const int CH = (n + 1023) / 1024;   // 20
    int t = threadIdx.x;
    int base = t * CH;
    int s = 0;
    for (int i = 0; i < CH; ++i) {
        int idx = base + i;
        if (idx < n) s += cnt[idx];
    }
    sums[t] = s;
    __syncthreads();
    for (int o = 1; o < 1024; o <<= 1) {
        int v = (t >= o) ? sums[t - o] : 0;
        __syncthreads();
        sums[t] += v;
        __syncthreads();
    }
    int run = (t == 0) ? 0 : sums[t - 1];
    for (int i = 0; i < CH; ++i) {
        int idx = base + i;
        if (idx < n) { row_ptr[idx] = run; run += cnt[idx]; }
    }
    if (t == 1023) row_ptr[n] = sums[1023];
}

__global__ void fill_csr(const int* __restrict__ ei, const int* __restrict__ row_ptr,
                         int* __restrict__ cur, int* __restrict__ col) {
    int j = blockIdx.x * blockDim.x + threadIdx.x;
    if (j >= ET_EDGES) return;
    int s, d;
    if (j < N_EDGES) { s = ei[j]; d = ei[N_EDGES + j]; }
    else             { s = d = j - N_EDGES; }
    int pos = row_ptr[d] + atomicAdd(&cur[d], 1);
    col[pos] = s;
}

// ---------------- fp32 SGEMM: C[M,Nc] = A[M,K] @ B[K,Nc] ----------------

__global__ __launch_bounds__(256) void sgemm64(const float* __restrict__ A,
                                               const float* __restrict__ B,
                                               float* __restrict__ C,
                                               int M, int K, int Nc) {
    __shared__ float As[16][64];
    __shared__ float Bs[16][64];
    int bm = blockIdx.x * 64;
    int bn = blockIdx.y * 64;
    int t = threadIdx.x;
    int tr = t >> 2, tq = t & 3;
    int bkr = t >> 4, bnq = t & 15;
    int tm = (t >> 4) * 4;
    int tn = (t & 15) * 4;
    float acc[4][4] = {};
    for (int k0 = 0; k0 < K; k0 += 16) {
        int ar = bm + tr;
        float4 av = make_float4(0.f, 0.f, 0.f, 0.f);
        if (ar < M) av = *(const float4*)&A[(size_t)ar * K + k0 + tq * 4];
        As[tq * 4 + 0][tr] = av.x;
        As[tq * 4 + 1][tr] = av.y;
        As[tq * 4 + 2][tr] = av.z;
        As[tq * 4 + 3][tr] = av.w;
        float4 bv = *(const float4*)&B[(size_t)(k0 + bkr) * Nc + bn + bnq * 4];
        *(float4*)&Bs[bkr][bnq * 4] = bv;
        __syncthreads();
        #pragma unroll
        for (int k = 0; k < 16; ++k) {
            float a[4], b[4];
            *(float4*)a = *(const float4*)&As[k][tm];
            *(float4*)b = *(const float4*)&Bs[k][tn];
            #pragma unroll
            for (int i = 0; i < 4; ++i)
                #pragma unroll
                for (int j = 0; j < 4; ++j)
                    acc[i][j] = fmaf(a[i], b[j], acc[i][j]);
        }
        __syncthreads();
    }
    #pragma unroll
    for (int i = 0; i < 4; ++i) {
        int r = bm + tm + i;
        if (r < M) {
            float4 o = make_float4(acc[i][0], acc[i][1], acc[i][2], acc[i][3]);
            *(float4*)&C[(size_t)r * Nc + bn + tn] = o;
        }
    }
}

// ---------------- per-node attention coefficients (transposed out) ---------

template <int HEADS, int C>
__global__ __launch_bounds__(256) void node_alpha2(const float* __restrict__ h,
                                                   const float* __restrict__ a_src,
                                                   const float* __restrict__ a_dst,
                                                   float* __restrict__ asT,   // [HEADS][N]
                                                   float* __restrict__ adT) { // [HEADS][N]
    constexpr int F = HEADS * C;
    constexpr int VEC = F / 64;        // 4 (F=256) or 2 (F=128)
    constexpr int LPH = C / VEC;       // lanes per head: 16 or 64
    int wid = threadIdx.x >> 6, lane = threadIdx.x & 63;
    int v = blockIdx.x * 4 + wid;
    if (v >= N_NODES) return;
    const float* hp = h + (size_t)v * F + lane * VEC;
    float ps = 0.f, pd = 0.f;
    #pragma unroll
    for (int c = 0; c < VEC; ++c) {
        float hv = hp[c];
        ps = fmaf(hv, a_src[lane * VEC + c], ps);
        pd = fmaf(hv, a_dst[lane * VEC + c], pd);
    }
    #pragma unroll
    for (int o = LPH / 2; o; o >>= 1) {
        ps += __shfl_xor(ps, o);
        pd += __shfl_xor(pd, o);
    }
    if ((lane & (LPH - 1)) == 0) {
        int head = lane / LPH;
        asT[head * N_NODES + v] = ps;
        adT[head * N_NODES + v] = pd;
    }
}

// ---------------- channel-sliced softmax-aggregate -------------------------
// Wave = (dst node, 32-channel slice). slice = blockIdx.x % NSLICE so with the
// %8 round-robin block->XCD mapping each XCD sees 1 (NSLICE=8) or 2 (NSLICE=4)
// slices: per-XCD gather working set = 20000*32*4 = 2.56 MB < 4 MiB L2.
// col loads and output stores are non-temporal so streaming data doesn't
// evict the gather table. 8 lanes x float4 = 128 B (one line) per edge-slice.

template <int NSLICE, int SCH, int F, int HEADS, bool DO_ELU>
__global__ __launch_bounds__(256) void gat_aggregate_sliced(
        const float* __restrict__ h,      // [N, F]
        const float* __restrict__ asT,    // [HEADS][N]
        const float* __restrict__ adT,    // [HEADS][N]
        const int* __restrict__ row_ptr,
        const int* __restrict__ col,
        const float* __restrict__ bias,   // [F]
        float* __restrict__ out) {        // [N, F]
    constexpr int CL = SCH / 4;           // lanes per edge (8)
    constexpr int E  = 64 / CL;           // parallel edges (8)
    constexpr int CPH = F / HEADS;        // channels per head
    __shared__ int2 s_op[4][64];          // (byte offset, p) per staged edge
    int slice = blockIdx.x & (NSLICE - 1);
    int ng = (int)(blockIdx.x / NSLICE);
    int wid = threadIdx.x >> 6, lane = threadIdx.x & 63;
    int v = ng * 4 + wid;
    if (v >= N_NODES) return;
    int head = (slice * SCH) / CPH;       // layers 1/2: slice>>1 ; layer 3: 0
    int eg = lane / CL, cl = lane % CL;
    int r0 = row_ptr[v], r1 = row_ptr[v + 1];
    float ad = adT[head * N_NODES + v];
    const float* asrc = asT + head * N_NODES;
    float acc[4] = {};
    float lsum = 0.f;
    const char* hb = (const char*)(h + slice * SCH + cl * 4);

    for (int base = r0; base < r1; base += 64) {
        int j = base + lane;
        bool valid = j < r1;
        int s = __builtin_nontemporal_load(&col[valid ? j : r0]);
        float e = asrc[s] + ad;
        e = (e > 0.f) ? e : NEG_SLOPE * e;
        float p = valid ? __expf(e) : 0.f;
        lsum += p;
        s_op[wid][lane] = make_int2(s * (F * 4), __float_as_int(p));

        int nk = min(64, r1 - base);
        int nkg = (nk + E - 1) / E;
        for (int g = 0; g < nkg; ++g) {
            int k = g * E + eg;           // may exceed nk: those have p=0
            int2 op = s_op[wid][k];
            float pk = __int_as_float(op.y);
            float4 hv = *(const float4*)(hb + op.x);
            acc[0] = fmaf(pk, hv.x, acc[0]);
            acc[1] = fmaf(pk, hv.y, acc[1]);
            acc[2] = fmaf(pk, hv.z, acc[2]);
            acc[3] = fmaf(pk, hv.w, acc[3]);
        }
    }
    // full-wave softmax denominator
    #pragma unroll
    for (int o = 32; o; o >>= 1) lsum += __shfl_xor(lsum, o);
    // reduce acc across edge groups (lanes differing in bits >= log2(CL))
    #pragma unroll
    for (int c = 0; c < 4; ++c) {
        #pragma unroll
        for (int o = CL; o < 64; o <<= 1) acc[c] += __shfl_xor(acc[c], o);
    }
    if (eg == 0) {
        float inv = 1.f / (lsum + 1e-16f);
        #pragma unroll
        for (int c = 0; c < 4; ++c) {
            int ch = slice * SCH + cl * 4 + c;
            float o = acc[c] * inv + bias[ch];
            if (DO_ELU) o = (o > 0.f) ? o : expm1f(o);
            __builtin_nontemporal_store(o, &out[(size_t)v * F + ch]);
        }
    }
}

// ---------------- global mean pool: 4-way row-split + atomic combine --------

__global__ void pool_mean4(const float* __restrict__ hout, const int* __restrict__ gstart,
                           float* __restrict__ gout) {
    int g = blockIdx.x;       // 64
    int q = blockIdx.y;       // 4 row-quarters
    int c = threadIdx.x;      // 128 channels
    int off = gstart[g], end = gstart[g + 1];
    float inv = 1.f / fmaxf((float)(end - off), 1.0f);
    float s = 0.f;
    for (int i = off + q; i < end; i += 4) s += hout[(size_t)i * 128 + c];
    atomicAdd(&gout[g * 128 + c], s * inv);
}

// ---------------- launch ----------------

static inline size_t align_up(size_t x, size_t a) { return (x + a - 1) & ~(a - 1); }

extern "C" void kernel_launch(void* const* d_in, const int* in_sizes, int n_in,
                              void* d_out, int out_size, void* d_ws, size_t ws_size,
                              hipStream_t stream) {
    const float* x   = (const float*)d_in[0];
    const int*   ei  = (const int*)d_in[1];
    const int*   bat = (const int*)d_in[2];
    const float* W1  = (const float*)d_in[3];
    const float* as1 = (const float*)d_in[4];
    const float* ad1 = (const float*)d_in[5];
    const float* b1  = (const float*)d_in[6];
    const float* W2  = (const float*)d_in[7];
    const float* as2 = (const float*)d_in[8];
    const float* ad2 = (const float*)d_in[9];
    const float* b2  = (const float*)d_in[10];
    const float* W3  = (const float*)d_in[11];
    const float* as3 = (const float*)d_in[12];
    const float* ad3 = (const float*)d_in[13];
    const float* b3  = (const float*)d_in[14];

    float* gout = (float*)d_out;                     // [G,128]
    float* hout = (float*)d_out + G_GRAPHS * 128;    // [N,128]

    char* w = (char*)d_ws;
    size_t o = 0;
    float* bufA = (float*)(w + o); o = align_up(o + (size_t)N_NODES * 256 * 4, 256);
    float* bufB = (float*)(w + o); o = align_up(o + (size_t)N_NODES * 256 * 4, 256);
    float* asv  = (float*)(w + o); o = align_up(o + (size_t)N_NODES * 4 * 4, 256);
    float* adv  = (float*)(w + o); o = align_up(o + (size_t)N_NODES * 4 * 4, 256);
    int* row_ptr = (int*)(w + o);  o = align_up(o + (size_t)(N_NODES + 1) * 4, 256);
    int* col     = (int*)(w + o);  o = align_up(o + (size_t)ET_EDGES * 4, 256);
    int* cnt     = (int*)(w + o);  o += (size_t)N_NODES * 4;        // cnt+cur contiguous
    int* cur     = (int*)(w + o);  o = align_up(o + (size_t)N_NODES * 4, 256);
    int* gstart  = (int*)(w + o);  o = align_up(o + (size_t)(G_GRAPHS + 1) * 4, 256);

    // ---- CSR build + graph bounds ----
    hipMemsetAsync(cnt, 0, (size_t)N_NODES * 8, stream);   // cnt AND cur
    hipMemsetAsync(gout, 0, (size_t)G_GRAPHS * 128 * 4, stream);
    hist_dst<<<(ET_EDGES + 255) / 256, 256, 0, stream>>>(ei, cnt, bat, gstart);
    scan_rowptr<<<1, 1024, 0, stream>>>(cnt, row_ptr);
    fill_csr<<<(ET_EDGES + 255) / 256, 256, 0, stream>>>(ei, row_ptr, cur, col);

    dim3 g4(313, 4), g2(313, 2);
    int nb = (N_NODES + 3) / 4;   // 4 nodes per block

    // ---- layer 1: 128 -> 4x64 ----
    sgemm64<<<g4, 256, 0, stream>>>(x, W1, bufA, N_NODES, 128, 256);
    node_alpha2<4, 64><<<nb, 256, 0, stream>>>(bufA, as1, ad1, asv, adv);
    gat_aggregate_sliced<8, 32, 256, 4, true><<<nb * 8, 256, 0, stream>>>(
        bufA, asv, adv, row_ptr, col, b1, bufB);

    // ---- layer 2: 256 -> 4x64 ----
    sgemm64<<<g4, 256, 0, stream>>>(bufB, W2, bufA, N_NODES, 256, 256);
    node_alpha2<4, 64><<<nb, 256, 0, stream>>>(bufA, as2, ad2, asv, adv);
    gat_aggregate_sliced<8, 32, 256, 4, true><<<nb * 8, 256, 0, stream>>>(
        bufA, asv, adv, row_ptr, col, b2, bufB);

    // ---- layer 3: 256 -> 128 (1 head, no concat, no elu) ----
    sgemm64<<<g2, 256, 0, stream>>>(bufB, W3, bufA, N_NODES, 256, 128);
    node_alpha2<1, 128><<<nb, 256, 0, stream>>>(bufA, as3, ad3, asv, adv);
    gat_aggregate_sliced<4, 32, 128, 1, false><<<nb * 4, 256, 0, stream>>>(
        bufA, asv, adv, row_ptr, col, b3, hout);

    // ---- global mean pool ----
    pool_mean4<<<dim3(G_GRAPHS, 4), 128, 0, stream>>>(hout, gstart, gout);
}

// Round 7
// 631.088 us; speedup vs baseline: 1.0365x; 1.0365x over previous
//
#include <hip/hip_runtime.h>
#include <hip/hip_bf16.h>
#include <math.h>

#define N_NODES 20000
#define N_EDGES 640000
#define ET_EDGES (N_EDGES + N_NODES)   // with self-loops
#define G_GRAPHS 64
#define NEG_SLOPE 0.2f

// ---------------- CSR construction (+ graph bounds folded in) ----------------

__global__ void hist_dst(const int* __restrict__ ei, int* __restrict__ cnt,
                         const int* __restrict__ batch, int* __restrict__ gstart) {
    int j = blockIdx.x * blockDim.x + threadIdx.x;
    if (blockIdx.x == 0 && threadIdx.x <= G_GRAPHS) {
        int g = threadIdx.x;
        int lo = 0, hi = N_NODES;
        while (lo < hi) {              // first i with batch[i] >= g
            int mid = (lo + hi) >> 1;
            if (batch[mid] < g) lo = mid + 1; else hi = mid;
        }
        gstart[g] = lo;
    }
    if (j >= ET_EDGES) return;
    int d = (j < N_EDGES) ? ei[N_EDGES + j] : (j - N_EDGES);
    atomicAdd(&cnt[d], 1);
}

__global__ __launch_bounds__(1024) void scan_rowptr(const int* __restrict__ cnt,
                                                    int* __restrict__ row_ptr) {
    __shared__ int sums[1024];
    const int n = N_NODES;
    const int CH = (n + 1023) / 1024;   // 20
    int t = threadIdx.x;
    int base = t * CH;
    int s = 0;
    for (int i = 0; i < CH; ++i) {
        int idx = base + i;
        if (idx < n) s += cnt[idx];
    }
    sums[t] = s;
    __syncthreads();
    for (int o = 1; o < 1024; o <<= 1) {
        int v = (t >= o) ? sums[t - o] : 0;
        __syncthreads();
        sums[t] += v;
        __syncthreads();
    }
    int run = (t == 0) ? 0 : sums[t - 1];
    for (int i = 0; i < CH; ++i) {
        int idx = base + i;
        if (idx < n) { row_ptr[idx] = run; run += cnt[idx]; }
    }
    if (t == 1023) row_ptr[n] = sums[1023];
}

__global__ void fill_csr(const int* __restrict__ ei, const int* __restrict__ row_ptr,
                         int* __restrict__ cur, int* __restrict__ col) {
    int j = blockIdx.x * blockDim.x + threadIdx.x;
    if (j >= ET_EDGES) return;
    int s, d;
    if (j < N_EDGES) { s = ei[j]; d = ei[N_EDGES + j]; }
    else             { s = d = j - N_EDGES; }
    int pos = row_ptr[d] + atomicAdd(&cur[d], 1);
    col[pos] = s;
}

// ---------------- fp32 SGEMM: C[M,Nc] = A[M,K] @ B[K,Nc] ----------------

__global__ __launch_bounds__(256) void sgemm64(const float* __restrict__ A,
                                               const float* __restrict__ B,
                                               float* __restrict__ C,
                                               int M, int K, int Nc) {
    __shared__ float As[16][64];
    __shared__ float Bs[16][64];
    int bm = blockIdx.x * 64;
    int bn = blockIdx.y * 64;
    int t = threadIdx.x;
    int tr = t >> 2, tq = t & 3;
    int bkr = t >> 4, bnq = t & 15;
    int tm = (t >> 4) * 4;
    int tn = (t & 15) * 4;
    float acc[4][4] = {};
    for (int k0 = 0; k0 < K; k0 += 16) {
        int ar = bm + tr;
        float4 av = make_float4(0.f, 0.f, 0.f, 0.f);
        if (ar < M) av = *(const float4*)&A[(size_t)ar * K + k0 + tq * 4];
        As[tq * 4 + 0][tr] = av.x;
        As[tq * 4 + 1][tr] = av.y;
        As[tq * 4 + 2][tr] = av.z;
        As[tq * 4 + 3][tr] = av.w;
        float4 bv = *(const float4*)&B[(size_t)(k0 + bkr) * Nc + bn + bnq * 4];
        *(float4*)&Bs[bkr][bnq * 4] = bv;
        __syncthreads();
        #pragma unroll
        for (int k = 0; k < 16; ++k) {
            float a[4], b[4];
            *(float4*)a = *(const float4*)&As[k][tm];
            *(float4*)b = *(const float4*)&Bs[k][tn];
            #pragma unroll
            for (int i = 0; i < 4; ++i)
                #pragma unroll
                for (int j = 0; j < 4; ++j)
                    acc[i][j] = fmaf(a[i], b[j], acc[i][j]);
        }
        __syncthreads();
    }
    #pragma unroll
    for (int i = 0; i < 4; ++i) {
        int r = bm + tm + i;
        if (r < M) {
            float4 o = make_float4(acc[i][0], acc[i][1], acc[i][2], acc[i][3]);
            *(float4*)&C[(size_t)r * Nc + bn + tn] = o;
        }
    }
}

// ---------------- per-node attention coefficients (transposed out) ---------

template <int HEADS, int C>
__global__ __launch_bounds__(256) void node_alpha2(const float* __restrict__ h,
                                                   const float* __restrict__ a_src,
                                                   const float* __restrict__ a_dst,
                                                   float* __restrict__ asT,   // [HEADS][N]
                                                   float* __restrict__ adT) { // [HEADS][N]
    constexpr int F = HEADS * C;
    constexpr int VEC = F / 64;        // 4 (F=256) or 2 (F=128)
    constexpr int LPH = C / VEC;       // lanes per head: 16 or 64
    int wid = threadIdx.x >> 6, lane = threadIdx.x & 63;
    int v = blockIdx.x * 4 + wid;
    if (v >= N_NODES) return;
    const float* hp = h + (size_t)v * F + lane * VEC;
    float ps = 0.f, pd = 0.f;
    #pragma unroll
    for (int c = 0; c < VEC; ++c) {
        float hv = hp[c];
        ps = fmaf(hv, a_src[lane * VEC + c], ps);
        pd = fmaf(hv, a_dst[lane * VEC + c], pd);
    }
    #pragma unroll
    for (int o = LPH / 2; o; o >>= 1) {
        ps += __shfl_xor(ps, o);
        pd += __shfl_xor(pd, o);
    }
    if ((lane & (LPH - 1)) == 0) {
        int head = lane / LPH;
        asT[head * N_NODES + v] = ps;
        adT[head * N_NODES + v] = pd;
    }
}

// ---------------- channel-sliced softmax-aggregate -------------------------
// Wave = (dst node, 32-channel slice). slice = blockIdx.x % NSLICE so with the
// %8 round-robin block->XCD mapping each XCD sees 1 (NSLICE=8) or 2 (NSLICE=4)
// slices: per-XCD gather working set = 20000*32*4 = 2.56 MB < 4 MiB L2.
// col loads are non-temporal (streaming, don't evict the gather table).
// Output stores: NORMAL cached, one float4 per lane (lane cl owns 4 contiguous
// channels) — L2 merges the 8 lanes into full 128-B lines. (NT scalar stores
// in round 6 caused 4x write amplification: partial-line HBM writes.)

template <int NSLICE, int SCH, int F, int HEADS, bool DO_ELU>
__global__ __launch_bounds__(256) void gat_aggregate_sliced(
        const float* __restrict__ h,      // [N, F]
        const float* __restrict__ asT,    // [HEADS][N]
        const float* __restrict__ adT,    // [HEADS][N]
        const int* __restrict__ row_ptr,
        const int* __restrict__ col,
        const float* __restrict__ bias,   // [F]
        float* __restrict__ out) {        // [N, F]
    constexpr int CL = SCH / 4;           // lanes per edge (8)
    constexpr int E  = 64 / CL;           // parallel edges (8)
    constexpr int CPH = F / HEADS;        // channels per head
    __shared__ int2 s_op[4][64];          // (byte offset, p) per staged edge
    int slice = blockIdx.x & (NSLICE - 1);
    int ng = (int)(blockIdx.x / NSLICE);
    int wid = threadIdx.x >> 6, lane = threadIdx.x & 63;
    int v = ng * 4 + wid;
    if (v >= N_NODES) return;
    int head = (slice * SCH) / CPH;       // layers 1/2: slice>>1 ; layer 3: 0
    int eg = lane / CL, cl = lane % CL;
    int r0 = row_ptr[v], r1 = row_ptr[v + 1];
    float ad = adT[head * N_NODES + v];
    const float* asrc = asT + head * N_NODES;
    float acc[4] = {};
    float lsum = 0.f;
    const char* hb = (const char*)(h + slice * SCH + cl * 4);

    for (int base = r0; base < r1; base += 64) {
        int j = base + lane;
        bool valid = j < r1;
        int s = __builtin_nontemporal_load(&col[valid ? j : r0]);
        float e = asrc[s] + ad;
        e = (e > 0.f) ? e : NEG_SLOPE * e;
        float p = valid ? __expf(e) : 0.f;
        lsum += p;
        s_op[wid][lane] = make_int2(s * (F * 4), __float_as_int(p));

        int nk = min(64, r1 - base);
        int nkg = (nk + E - 1) / E;
        for (int g = 0; g < nkg; ++g) {
            int k = g * E + eg;           // may exceed nk: those have p=0
            int2 op = s_op[wid][k];
            float pk = __int_as_float(op.y);
            float4 hv = *(const float4*)(hb + op.x);
            acc[0] = fmaf(pk, hv.x, acc[0]);
            acc[1] = fmaf(pk, hv.y, acc[1]);
            acc[2] = fmaf(pk, hv.z, acc[2]);
            acc[3] = fmaf(pk, hv.w, acc[3]);
        }
    }
    // full-wave softmax denominator
    #pragma unroll
    for (int o = 32; o; o >>= 1) lsum += __shfl_xor(lsum, o);
    // reduce acc across edge groups (lanes differing in bits >= log2(CL))
    #pragma unroll
    for (int c = 0; c < 4; ++c) {
        #pragma unroll
        for (int o = CL; o < 64; o <<= 1) acc[c] += __shfl_xor(acc[c], o);
    }
    if (eg == 0) {
        float inv = 1.f / (lsum + 1e-16f);
        int ch0 = slice * SCH + cl * 4;
        float4 ov;
        float* po = &ov.x;
        #pragma unroll
        for (int c = 0; c < 4; ++c) {
            float o = acc[c] * inv + bias[ch0 + c];
            if (DO_ELU) o = (o > 0.f) ? o : expm1f(o);
            po[c] = o;
        }
        *(float4*)&out[(size_t)v * F + ch0] = ov;
    }
}

// ---------------- global mean pool: 4-way row-split + atomic combine --------

__global__ void pool_mean4(const float* __restrict__ hout, const int* __restrict__ gstart,
                           float* __restrict__ gout) {
    int g = blockIdx.x;       // 64
    int q = blockIdx.y;       // 4 row-quarters
    int c = threadIdx.x;      // 128 channels
    int off = gstart[g], end = gstart[g + 1];
    float inv = 1.f / fmaxf((float)(end - off), 1.0f);
    float s = 0.f;
    for (int i = off + q; i < end; i += 4) s += hout[(size_t)i * 128 + c];
    atomicAdd(&gout[g * 128 + c], s * inv);
}

// ---------------- launch ----------------

static inline size_t align_up(size_t x, size_t a) { return (x + a - 1) & ~(a - 1); }

extern "C" void kernel_launch(void* const* d_in, const int* in_sizes, int n_in,
                              void* d_out, int out_size, void* d_ws, size_t ws_size,
                              hipStream_t stream) {
    const float* x   = (const float*)d_in[0];
    const int*   ei  = (const int*)d_in[1];
    const int*   bat = (const int*)d_in[2];
    const float* W1  = (const float*)d_in[3];
    const float* as1 = (const float*)d_in[4];
    const float* ad1 = (const float*)d_in[5];
    const float* b1  = (const float*)d_in[6];
    const float* W2  = (const float*)d_in[7];
    const float* as2 = (const float*)d_in[8];
    const float* ad2 = (const float*)d_in[9];
    const float* b2  = (const float*)d_in[10];
    const float* W3  = (const float*)d_in[11];
    const float* as3 = (const float*)d_in[12];
    const float* ad3 = (const float*)d_in[13];
    const float* b3  = (const float*)d_in[14];

    float* gout = (float*)d_out;                     // [G,128]
    float* hout = (float*)d_out + G_GRAPHS * 128;    // [N,128]

    char* w = (char*)d_ws;
    size_t o = 0;
    float* bufA = (float*)(w + o); o = align_up(o + (size_t)N_NODES * 256 * 4, 256);
    float* bufB = (float*)(w + o); o = align_up(o + (size_t)N_NODES * 256 * 4, 256);
    float* asv  = (float*)(w + o); o = align_up(o + (size_t)N_NODES * 4 * 4, 256);
    float* adv  = (float*)(w + o); o = align_up(o + (size_t)N_NODES * 4 * 4, 256);
    int* row_ptr = (int*)(w + o);  o = align_up(o + (size_t)(N_NODES + 1) * 4, 256);
    int* col     = (int*)(w + o);  o = align_up(o + (size_t)ET_EDGES * 4, 256);
    int* cnt     = (int*)(w + o);  o += (size_t)N_NODES * 4;        // cnt+cur contiguous
    int* cur     = (int*)(w + o);  o = align_up(o + (size_t)N_NODES * 4, 256);
    int* gstart  = (int*)(w + o);  o = align_up(o + (size_t)(G_GRAPHS + 1) * 4, 256);

    // ---- CSR build + graph bounds ----
    hipMemsetAsync(cnt, 0, (size_t)N_NODES * 8, stream);   // cnt AND cur
    hipMemsetAsync(gout, 0, (size_t)G_GRAPHS * 128 * 4, stream);
    hist_dst<<<(ET_EDGES + 255) / 256, 256, 0, stream>>>(ei, cnt, bat, gstart);
    scan_rowptr<<<1, 1024, 0, stream>>>(cnt, row_ptr);
    fill_csr<<<(ET_EDGES + 255) / 256, 256, 0, stream>>>(ei, row_ptr, cur, col);

    dim3 g4(313, 4), g2(313, 2);
    int nb = (N_NODES + 3) / 4;   // 4 nodes per block

    // ---- layer 1: 128 -> 4x64 ----
    sgemm64<<<g4, 256, 0, stream>>>(x, W1, bufA, N_NODES, 128, 256);
    node_alpha2<4, 64><<<nb, 256, 0, stream>>>(bufA, as1, ad1, asv, adv);
    gat_aggregate_sliced<8, 32, 256, 4, true><<<nb * 8, 256, 0, stream>>>(
        bufA, asv, adv, row_ptr, col, b1, bufB);

    // ---- layer 2: 256 -> 4x64 ----
    sgemm64<<<g4, 256, 0, stream>>>(bufB, W2, bufA, N_NODES, 256, 256);
    node_alpha2<4, 64><<<nb, 256, 0, stream>>>(bufA, as2, ad2, asv, adv);
    gat_aggregate_sliced<8, 32, 256, 4, true><<<nb * 8, 256, 0, stream>>>(
        bufA, asv, adv, row_ptr, col, b2, bufB);

    // ---- layer 3: 256 -> 128 (1 head, no concat, no elu) ----
    sgemm64<<<g2, 256, 0, stream>>>(bufB, W3, bufA, N_NODES, 256, 128);
    node_alpha2<1, 128><<<nb, 256, 0, stream>>>(bufA, as3, ad3, asv, adv);
    gat_aggregate_sliced<4, 32, 128, 1, false><<<nb * 4, 256, 0, stream>>>(
        bufA, asv, adv, row_ptr, col, b3, hout);

    // ---- global mean pool ----
    pool_mean4<<<dim3(G_GRAPHS, 4), 128, 0, stream>>>(hout, gstart, gout);
}